// Round 8
// baseline (172.082 us; speedup 1.0000x reference)
//
#include <hip/hip_runtime.h>
#include <hip/hip_bf16.h>
#include <math.h>

// Problem constants
#define B_    8
#define T_    2048
#define NTOK  (B_ * T_)   // 16384 tokens
#define D_    512
#define E_    8
#define NPAIR 28          // unordered expert pairs (top-2 always distinct)
#define CAP   NTOK        // per-pair bucket capacity (worst case)

// router v6: 1024 blocks x 256 thr; 16 tok/block, 4 tok/wave.
#define RV_TOK    16
#define RV_THR    256
#define XS_STRIDE 132
#define WS_FLOATS 2108

typedef __attribute__((ext_vector_type(4))) float f32x4;
typedef __attribute__((ext_vector_type(8))) short short8;  // 8 bf16 (MFMA a/b frag)

__device__ __forceinline__ void async_load16(const void* g, void* l) {
    __builtin_amdgcn_global_load_lds(
        (const __attribute__((address_space(1))) unsigned int*)g,
        (__attribute__((address_space(3))) unsigned int*)l,
        16, 0, 0);
}

// ---------------------------------------------------------------------------
// Kernel 1: Wk[e][d][h] fp32 -> Wkt[e][h][d] bf16 (B^T layout for GEMM).
// ---------------------------------------------------------------------------
__global__ __launch_bounds__(256) void transpose_wk(
    const float* __restrict__ Wk, __hip_bfloat16* __restrict__ Wkt)
{
    __shared__ float tile[32][33];
    const int e  = blockIdx.z;
    const int d0 = blockIdx.x * 32;
    const int h0 = blockIdx.y * 32;
    const int tx = threadIdx.x, ty = threadIdx.y;

    const float* src = Wk + ((size_t)e * D_ + d0) * D_ + h0;
    #pragma unroll
    for (int r = ty; r < 32; r += 8)
        tile[r][tx] = src[(size_t)r * D_ + tx];
    __syncthreads();
    __hip_bfloat16* dst = Wkt + ((size_t)e * D_ + h0) * D_ + d0;
    #pragma unroll
    for (int r = ty; r < 32; r += 8)
        dst[(size_t)r * D_ + tx] = __float2bfloat16(tile[tx][r]);
}

// ---------------------------------------------------------------------------
// Kernel 2: router v6 (unchanged). x staged+bf16-converted once, W staged
// per 128-k chunk, fp32 fma, k-split lanes; 1024 blocks (4 waves/SIMD).
// ---------------------------------------------------------------------------
__global__ __launch_bounds__(RV_THR) void router_kernel(
    const float* __restrict__ x,     // [NTOK][D]
    const float* __restrict__ eps,   // [NTOK][E]
    const float* __restrict__ Wr,    // [D][E]
    const float* __restrict__ br,    // [E]
    const float* __restrict__ Wn,    // [D][E]
    const float* __restrict__ bn,    // [E]
    __hip_bfloat16* __restrict__ xb, // out: [NTOK][D] bf16
    uint4* __restrict__ top2)        // out: [NTOK] {i1|i2<<8, g1bits, g2bits}
{
    __shared__ float xs[RV_TOK * XS_STRIDE];  // 8.4 KB
    __shared__ float wsh[WS_FLOATS];          // 8.4 KB; row k at k*16+(k>>3)*4

    const int tid  = threadIdx.x;
    const int tok0 = blockIdx.x * RV_TOK;
    const int lane = tid & 63, wv = tid >> 6;
    const int kidx = lane >> 2, ts = lane & 3;
    const int tl = wv * 4 + ts;                // this lane's token
    const int wk = tid >> 1, wh = tid & 1;     // W stager: row, half

    float acc[16];  // [0..7]=x.Wr per expert, [8..15]=x.Wn
    #pragma unroll
    for (int c = 0; c < 16; ++c) acc[c] = 0.f;

    for (int kc = 0; kc < D_; kc += 128) {
        // stage x chunk [16 tok][128 k] + fused bf16 convert/store
        #pragma unroll
        for (int it = 0; it < 2; ++it) {
            const int f   = it * RV_THR + tid;      // f32x4 index in [0,512)
            const int row = f >> 5, col = (f & 31) * 4;
            const f32x4 v = *(const f32x4*)(x + (size_t)(tok0 + row) * D_ + kc + col);
            *(f32x4*)(xs + row * XS_STRIDE + col) = v;
            union { __hip_bfloat16 h[4]; uint2 u; } cv;
            cv.h[0] = __float2bfloat16(v.x); cv.h[1] = __float2bfloat16(v.y);
            cv.h[2] = __float2bfloat16(v.z); cv.h[3] = __float2bfloat16(v.w);
            *(uint2*)(xb + (size_t)(tok0 + row) * D_ + kc + col) = cv.u;
        }
        // stage W chunk [128 k][16 c] skewed; cols 0-7 = Wr, 8-15 = Wn
        {
            const float* src = (wh ? Wn : Wr) + (size_t)(kc + wk) * E_;
            const f32x4 w0 = *(const f32x4*)(src);
            const f32x4 w1 = *(const f32x4*)(src + 4);
            float* dst = wsh + wk * 16 + (wk >> 3) * 4 + wh * 8;
            *(f32x4*)(dst)     = w0;
            *(f32x4*)(dst + 4) = w1;
        }
        __syncthreads();

        // compute: this lane's 8 k-values of the chunk (k = kidx*8 + kk)
        const float* xra = xs + tl * XS_STRIDE + kidx * 8;
        const f32x4 xa0 = *(const f32x4*)(xra);
        const f32x4 xa1 = *(const f32x4*)(xra + 4);
        const float* wbase = wsh + kidx * 132;  // (kidx*8)*16 + kidx*4
        #pragma unroll
        for (int kk = 0; kk < 8; ++kk) {
            const float xav = (kk < 4) ? xa0[kk] : xa1[kk - 4];
            const float* wrow = wbase + kk * 16;
            #pragma unroll
            for (int c4 = 0; c4 < 4; ++c4) {
                const f32x4 w = *(const f32x4*)(wrow + c4 * 4);
                #pragma unroll
                for (int c = 0; c < 4; ++c)
                    acc[c4 * 4 + c] = fmaf(xav, w[c], acc[c4 * 4 + c]);
            }
        }
        __syncthreads();
    }

    // reduce across the 16 kidx lanes (stride 4): xor 4,8,16,32
    #pragma unroll
    for (int off = 4; off < 64; off <<= 1) {
        #pragma unroll
        for (int c = 0; c < 16; ++c)
            acc[c] += __shfl_xor(acc[c], off);
    }

    if (lane < 4) {  // kidx==0 lanes hold full dots for token tl
        const int tok = tok0 + tl;
        float nv[8];
        #pragma unroll
        for (int e = 0; e < 8; ++e) {
            const float nl = acc[8 + e] + bn[e];
            // jax.nn.softplus = max(z,0) + log1p(exp(-|z|))
            const float sp = fmaxf(nl, 0.f) + log1pf(expf(-fabsf(nl)));
            nv[e] = acc[e] + br[e] + eps[(size_t)tok * E_ + e] * sp;
        }
        // top-2, lax.top_k tie semantics (lowest index wins ties)
        int i1 = 0; float v1 = nv[0];
        #pragma unroll
        for (int e = 1; e < 8; ++e)
            if (nv[e] > v1) { v1 = nv[e]; i1 = e; }
        int i2 = -1; float v2 = -3.4e38f;
        #pragma unroll
        for (int e = 0; e < 8; ++e)
            if (e != i1 && nv[e] > v2) { v2 = nv[e]; i2 = e; }
        const float t  = expf(v2 - v1);
        const float g1 = 1.f / (1.f + t);
        const float g2 = t / (1.f + t);
        top2[tok] = make_uint4((unsigned)i1 | ((unsigned)i2 << 8),
                               __float_as_uint(g1), __float_as_uint(g2), 0u);
    }
}

// ---------------------------------------------------------------------------
// Kernel 3: PAIR bucket build (unchanged). p = a*(15-a)/2 + (b-a-1).
// Entry: {tok, gate(e_lo), gate(e_hi), 0}.
// ---------------------------------------------------------------------------
__global__ __launch_bounds__(256) void bucket_kernel(
    const uint4* __restrict__ top2,
    int* __restrict__ counts,     // [NPAIR] pre-zeroed
    uint4* __restrict__ entries)  // [NPAIR][CAP]
{
    __shared__ int hist[NPAIR];
    __shared__ int base[NPAIR];
    const int tid = threadIdx.x;
    const int tok = blockIdx.x * 256 + tid;
    if (tid < NPAIR) hist[tid] = 0;
    __syncthreads();
    const uint4 t = top2[tok];
    const int i1 = t.x & 0xff, i2 = (t.x >> 8) & 0xff;
    const int a = min(i1, i2), b = max(i1, i2);
    const unsigned ga = (i1 < i2) ? t.y : t.z;
    const unsigned gb = (i1 < i2) ? t.z : t.y;
    const int p = a * (15 - a) / 2 + (b - a - 1);
    const int l = atomicAdd(&hist[p], 1);
    __syncthreads();
    if (tid < NPAIR) base[tid] = atomicAdd(counts + tid, hist[tid]);
    __syncthreads();
    entries[(size_t)p * CAP + base[p] + l] = make_uint4((unsigned)tok, ga, gb, 0u);
}

// ---------------------------------------------------------------------------
// Kernel 4: pair-grouped GEMM v3. BM=128 x BN=64 x 2 experts, BK=32.
// Wave = 32 rows x 64 cols x 2 experts (acc 64 VGPR -> 3 blocks/CU vs R7's
// 2; R7's dual-128-col acc at 2 waves/SIMD was the occupancy cliff).
// XOR-swizzled LDS: chunk c of row r lives at slot (c+(r>>1))&3 -- kills
// the measured 8-way ds_read_b128 bank conflict (1.7M cyc in R7); staging
// keeps global_load_lds (dest lane*16 fixed; only the SOURCE chunk index
// is permuted, same 64B line per 4-lane group -> coalescing unchanged).
// Epilogue: direct fp32 stores out = ga*(C1+bk1)+gb*(C2+bk2).
// ---------------------------------------------------------------------------
__global__ __launch_bounds__(256, 3) void moe_gemm(
    const __hip_bfloat16* __restrict__ xb,   // [NTOK][D] bf16
    const __hip_bfloat16* __restrict__ wkt,  // [E][D(out)][D(in)] bf16 (B^T)
    const float* __restrict__ bk,            // [E][D]
    const int* __restrict__ counts,          // [NPAIR]
    const uint4* __restrict__ entries,       // [NPAIR][CAP]
    float* __restrict__ out)                 // [NTOK][D] fp32 (fully written)
{
    constexpr int BM = 128, BN = 64, BK = 32;
    __shared__ __hip_bfloat16 As[BM * BK];       // 8 KB
    __shared__ __hip_bfloat16 Bs[2][BN * BK];    // 8 KB
    __shared__ uint4 ent[BM];                    // 2 KB

    const int p  = blockIdx.z;
    const int mt = blockIdx.y;
    const int nt = blockIdx.x;
    const int cnt = counts[p];
    if (mt * BM >= cnt) return;

    // decode pair p -> (e1 < e2)
    int e1 = 0, rem = p;
    while (rem >= 7 - e1) { rem -= 7 - e1; ++e1; }
    const int e2 = e1 + 1 + rem;

    const int tid = threadIdx.x;
    const int w = tid >> 6, lane = tid & 63;

    if (tid < BM) {
        const int idx = mt * BM + tid;
        ent[tid] = (idx < cnt) ? entries[(size_t)p * CAP + idx]
                               : make_uint4(0u, 0u, 0u, 0u);
    }
    __syncthreads();

    const int quad = lane >> 4, lr = lane & 15;
    const int sub = lane >> 2, part = lane & 3;

    f32x4 acc[2][4][2];  // [row tile][col tile][expert]
    #pragma unroll
    for (int i = 0; i < 2; ++i)
        #pragma unroll
        for (int j = 0; j < 4; ++j)
            #pragma unroll
            for (int m = 0; m < 2; ++m)
                acc[i][j][m] = (f32x4){0.f, 0.f, 0.f, 0.f};

    // A staging: wave w stages rows w*32 + {0,16} + sub (token gather)
    const size_t tokA0 = ent[w * 32 + sub].x;
    const size_t tokA1 = ent[w * 32 + 16 + sub].x;
    // swizzle: slot `part` of row r holds global chunk (part - (r>>1)) & 3;
    // rowbase is a multiple of 16 so only (sub>>1)&3 matters.
    const int csw = (part - ((sub >> 1) & 3)) & 3;
    // B staging: wave w stages buffer m=w>>1 rows (w&1)*32 + {0,16} + sub
    const int mB = w >> 1;
    const int brow0 = (w & 1) * 32 + sub;
    const int eb = mB ? e2 : e1;
    const size_t gB0 = (size_t)eb * D_ + nt * BN + brow0;

    for (int k0 = 0; k0 < D_; k0 += BK) {
        async_load16(xb + tokA0 * D_ + k0 + csw * 8, As + (w * 32) * BK);
        async_load16(xb + tokA1 * D_ + k0 + csw * 8, As + (w * 32 + 16) * BK);
        async_load16(wkt + gB0 * D_ + k0 + csw * 8, Bs[mB] + brow0 * BK - sub * BK + sub * BK);
        // (the line above simplifies to base (w&1)*32*BK; keep explicit:)
        async_load16(wkt + (gB0 + 16) * D_ + k0 + csw * 8,
                     Bs[mB] + ((w & 1) * 32 + 16) * BK);
        __syncthreads();

        short8 a[2], b[2][4];
        const int rsw = (quad + ((lr >> 1) & 3)) & 3;  // read slot for chunk `quad`
        #pragma unroll
        for (int i = 0; i < 2; ++i)
            a[i] = *(const short8*)(As + (w * 32 + i * 16 + lr) * BK + rsw * 8);
        #pragma unroll
        for (int m = 0; m < 2; ++m)
            #pragma unroll
            for (int j = 0; j < 4; ++j)
                b[m][j] = *(const short8*)(Bs[m] + (j * 16 + lr) * BK + rsw * 8);
        #pragma unroll
        for (int i = 0; i < 2; ++i)
            #pragma unroll
            for (int j = 0; j < 4; ++j)
                #pragma unroll
                for (int m = 0; m < 2; ++m)
                    acc[i][j][m] = __builtin_amdgcn_mfma_f32_16x16x32_bf16(
                        a[i], b[m][j], acc[i][j][m], 0, 0, 0);
        __syncthreads();
    }

    const int colbase = nt * BN + lr;
    float bkA[4], bkB[4];
    #pragma unroll
    for (int j = 0; j < 4; ++j) {
        bkA[j] = bk[e1 * D_ + colbase + j * 16];
        bkB[j] = bk[e2 * D_ + colbase + j * 16];
    }

    #pragma unroll
    for (int i = 0; i < 2; ++i) {
        #pragma unroll
        for (int r = 0; r < 4; ++r) {
            const int row = w * 32 + i * 16 + quad * 4 + r;  // C: row = quad*4+reg
            if (mt * BM + row < cnt) {
                const uint4 en = ent[row];
                const float ga = __uint_as_float(en.y);
                const float gb = __uint_as_float(en.z);
                float* orow = out + (size_t)en.x * D_ + colbase;
                #pragma unroll
                for (int j = 0; j < 4; ++j)
                    orow[j * 16] = ga * (acc[i][j][0][r] + bkA[j])
                                 + gb * (acc[i][j][1][r] + bkB[j]);
            }
        }
    }
}

// ---------------------------------------------------------------------------
// Launch
// ---------------------------------------------------------------------------
extern "C" void kernel_launch(void* const* d_in, const int* in_sizes, int n_in,
                              void* d_out, int out_size, void* d_ws, size_t ws_size,
                              hipStream_t stream) {
    const float* x   = (const float*)d_in[0];
    const float* eps = (const float*)d_in[1];
    const float* Wr  = (const float*)d_in[2];
    const float* br  = (const float*)d_in[3];
    const float* Wn  = (const float*)d_in[4];
    const float* bn  = (const float*)d_in[5];
    const float* Wk  = (const float*)d_in[6];
    const float* bk  = (const float*)d_in[7];
    float* out = (float*)d_out;

    // workspace layout (256B-aligned): ~28 MB total
    char* ws = (char*)d_ws;
    size_t off = 0;
    int* counts = (int*)(ws + off);                     off += 256;
    uint4* entries = (uint4*)(ws + off);                off += (size_t)NPAIR * CAP * 16;  // 7.3 MiB
    __hip_bfloat16* xb = (__hip_bfloat16*)(ws + off);   off += (size_t)NTOK * D_ * 2;     // 16 MiB
    __hip_bfloat16* wkt = (__hip_bfloat16*)(ws + off);  off += (size_t)E_ * D_ * D_ * 2;  // 4 MiB
    uint4* top2 = (uint4*)(ws + off);                   off += (size_t)NTOK * 16;         // 256 KiB
    (void)ws_size;

    hipMemsetAsync(counts, 0, NPAIR * sizeof(int), stream);

    transpose_wk<<<dim3(16, 16, E_), dim3(32, 8), 0, stream>>>(Wk, wkt);
    router_kernel<<<dim3(NTOK / RV_TOK), dim3(RV_THR), 0, stream>>>(
        x, eps, Wr, br, Wn, bn, xb, top2);
    bucket_kernel<<<dim3(NTOK / 256), dim3(256), 0, stream>>>(top2, counts, entries);
    moe_gemm<<<dim3(D_ / 64, CAP / 128, NPAIR), dim3(256), 0, stream>>>(
        xb, wkt, bk, counts, entries, out);
}